// Round 2
// 766.364 us; speedup vs baseline: 1.0021x; 1.0021x over previous
//
#include <hip/hip_runtime.h>

#define NN 10000
#define NE 160000
#define FIN 1152
#define FOUT 288
#define FOUT_TOTAL 1152
#define NF (NN * FOUT)          /* 2,880,000 elems per N x 288 panel */
#define WSL (FIN * FOUT)        /* 331,776 elems per (conv,k) weight slice */
#define NSLICE 22

typedef __attribute__((ext_vector_type(8))) short short8;
typedef __attribute__((ext_vector_type(8))) unsigned short ushort8v;
typedef __attribute__((ext_vector_type(4))) float floatx4;

__device__ __forceinline__ unsigned short f2bf(float f) {
  unsigned int u = __float_as_uint(f);
  u += 0x7FFF + ((u >> 16) & 1); // round-to-nearest-even
  return (unsigned short)(u >> 16);
}
__device__ __forceinline__ float bf2f(unsigned short u) {
  return __uint_as_float(((unsigned int)u) << 16);
}

// async global->LDS, 16B per lane. LDS dest MUST be wave-uniform base + lane*16.
__device__ __forceinline__ void async_copy16(void* lds, const void* gmem) {
  __builtin_amdgcn_global_load_lds(
      (const __attribute__((address_space(1))) unsigned int*)gmem,
      (__attribute__((address_space(3))) unsigned int*)lds, 16, 0, 0);
}

// ---------------- degree / normalization ----------------

__global__ void deg_kernel(const int* __restrict__ ei, int* __restrict__ deg,
                           int* __restrict__ indeg) {
  int e = blockIdx.x * 256 + threadIdx.x;
  if (e < NE) {
    atomicAdd(&deg[ei[e]], 1);        // out-degree by source (row)
    atomicAdd(&indeg[ei[NE + e]], 1); // in-degree by target (col)
  }
}

__global__ void dinv_kernel(const int* __restrict__ deg, float* __restrict__ dinv) {
  int i = blockIdx.x * 256 + threadIdx.x;
  if (i < NN) {
    int d = deg[i];
    dinv[i] = d > 0 ? rsqrtf((float)d) : 0.0f;
  }
}

// single-block exclusive scan of indeg -> rowptr (and cursor copy)
__global__ void scan_kernel(const int* __restrict__ indeg, int* __restrict__ rowptr,
                            int* __restrict__ cursor) {
  __shared__ int s[256];
  __shared__ int carry_s;
  if (threadIdx.x == 0) carry_s = 0;
  __syncthreads();
  for (int base = 0; base < NN; base += 256) {
    int i = base + threadIdx.x;
    int v = (i < NN) ? indeg[i] : 0;
    s[threadIdx.x] = v;
    __syncthreads();
    for (int off = 1; off < 256; off <<= 1) {
      int t = (threadIdx.x >= off) ? s[threadIdx.x - off] : 0;
      __syncthreads();
      s[threadIdx.x] += t;
      __syncthreads();
    }
    int excl = s[threadIdx.x] - v + carry_s;
    if (i < NN) { rowptr[i] = excl; cursor[i] = excl; }
    __syncthreads();
    if (threadIdx.x == 0) carry_s += s[255];
    __syncthreads();
  }
  if (threadIdx.x == 0) rowptr[NN] = carry_s;
}

__global__ void scatter_kernel(const int* __restrict__ ei, const float* __restrict__ dinv,
                               int* __restrict__ cursor, int* __restrict__ srcarr,
                               float* __restrict__ wn) {
  int e = blockIdx.x * 256 + threadIdx.x;
  if (e < NE) {
    int r = ei[e], c = ei[NE + e];
    int pos = atomicAdd(&cursor[c], 1);
    srcarr[pos] = r;
    wn[pos] = -(dinv[r] * dinv[c]);
  }
}

// ---------------- weight transpose+cast: Wt[slice][o][f] bf16 ----------------
__global__ void wtrans_kernel(const float* __restrict__ W0, const float* __restrict__ W1,
                              const float* __restrict__ W2, const float* __restrict__ W3,
                              unsigned short* __restrict__ Wt) {
  int i = blockIdx.x * 256 + threadIdx.x;
  if (i >= NSLICE * WSL) return;
  int s = i / WSL;
  int rem = i - s * WSL;
  int o = rem / FIN;
  int f = rem - o * FIN;
  int c, k;
  if (s < 4)       { c = 0; k = s; }
  else if (s < 9)  { c = 1; k = s - 4; }
  else if (s < 15) { c = 2; k = s - 9; }
  else             { c = 3; k = s - 15; }
  const float* W = (c == 0) ? W0 : (c == 1) ? W1 : (c == 2) ? W2 : W3;
  Wt[i] = f2bf(W[(size_t)k * WSL + (size_t)f * FOUT + o]);
}

// ---------------- x -> bf16 cast ----------------
__global__ void xcast_kernel(const float* __restrict__ x, unsigned short* __restrict__ xb) {
  int i = blockIdx.x * 256 + threadIdx.x; // one float4 group per thread
  if (i < NN * FIN / 4) {
    float4 v = *(const float4*)(x + (size_t)i * 4);
    ushort4 r;
    r.x = f2bf(v.x); r.y = f2bf(v.y); r.z = f2bf(v.z); r.w = f2bf(v.w);
    *(ushort4*)(xb + (size_t)i * 4) = r;
  }
}

// ---------------- MFMA GEMM: Y[slice] = bf16( xb @ Wt[slice]^T ) ----------------
// Block tile 128x96, K=1152 (BK=64), 4 waves in 2x2, wave tile 64x48 = 4x3 mfma frags.
// Grid: x = (slice, ntile) [66], y = mtile [79].
// LDS XOR-swizzle (T2, rule 21): global_load_lds writes lane-linear, so the
// swizzle is applied to the GLOBAL source column (chunk ^= row&7) and the same
// XOR on the ds_read column. Unswizzled, the fragment reads hit 16 banks with
// 16 accesses/bank (row stride = 128 B); swizzled, 64 lanes cover all 32 banks
// at the 8-access/bank ds_read_b128 floor.
__global__ __launch_bounds__(256) void gemm_mfma_kernel(
    const unsigned short* __restrict__ Xb, const unsigned short* __restrict__ Wt,
    unsigned short* __restrict__ Yall) {
  const int bx = blockIdx.x;
  const int slice = bx / 3;
  const int n0 = (bx - slice * 3) * 96;
  const int m0 = blockIdx.y * 128;

  __shared__ unsigned short As[128][64]; // [m][k] rows of 128 B (chunk-swizzled)
  __shared__ unsigned short Bs[96][64];  // [o][f] (chunk-swizzled)

  const int tid = threadIdx.x;
  const int lane = tid & 63;
  const int wave = tid >> 6;
  const int wx = wave & 1;        // n-dir
  const int wy = wave >> 1;       // m-dir
  const int lm = lane & 15;
  const int hi = lane >> 4;       // 16B chunk sub-index within 64B k-phase

  floatx4 acc[4][3];
#pragma unroll
  for (int i = 0; i < 4; i++)
#pragma unroll
    for (int j = 0; j < 3; j++) acc[i][j] = (floatx4){0.f, 0.f, 0.f, 0.f};

  const unsigned short* Wbase = Wt + (size_t)slice * WSL;

  for (int f0 = 0; f0 < FIN; f0 += 64) {
    __syncthreads(); // protect LDS from previous iteration's readers
    // stage A: 128 rows x 128 B, lane-linear LDS dest, swizzled global source
#pragma unroll
    for (int i = 0; i < 4; i++) {
      int idx = i * 256 + tid;
      int row = idx >> 3;
      int ck = idx & 7;
      int gr = m0 + row;
      gr = gr < NN ? gr : NN - 1; // clamp (masked at store)
      async_copy16((char*)&As[0][0] + idx * 16,
                   (const char*)Xb + ((size_t)gr * FIN + f0) * 2 + ((ck ^ (row & 7)) << 4));
    }
    // stage B: 96 rows x 128 B
#pragma unroll
    for (int i = 0; i < 3; i++) {
      int idx = i * 256 + tid;
      int row = idx >> 3;
      int ck = idx & 7;
      async_copy16((char*)&Bs[0][0] + idx * 16,
                   (const char*)Wbase + ((size_t)(n0 + row) * FIN + f0) * 2 + ((ck ^ (row & 7)) << 4));
    }
    __syncthreads();
#pragma unroll
    for (int s = 0; s < 2; s++) {
      short8 a[4], b[3];
#pragma unroll
      for (int i = 0; i < 4; i++) {
        int ar = wy * 64 + i * 16 + lm;
        a[i] = *(const short8*)((const char*)&As[ar][0] + (((s * 4 + hi) ^ (ar & 7)) << 4));
      }
#pragma unroll
      for (int j = 0; j < 3; j++) {
        int br = wx * 48 + j * 16 + lm;
        b[j] = *(const short8*)((const char*)&Bs[br][0] + (((s * 4 + hi) ^ (br & 7)) << 4));
      }
#pragma unroll
      for (int i = 0; i < 4; i++)
#pragma unroll
        for (int j = 0; j < 3; j++)
          acc[i][j] = __builtin_amdgcn_mfma_f32_16x16x32_bf16(a[i], b[j], acc[i][j], 0, 0, 0);
    }
  }
  // epilogue: C/D layout col=lane&15, row=(lane>>4)*4+reg -> bf16 Y panel
  unsigned short* Yb = Yall + (size_t)slice * NF;
  const int cbase = n0 + wx * 48 + lm;
  const int rbase = (lane >> 4) * 4;
#pragma unroll
  for (int i = 0; i < 4; i++) {
#pragma unroll
    for (int r = 0; r < 4; r++) {
      int grow = m0 + wy * 64 + i * 16 + rbase + r;
      if (grow < NN) {
        unsigned short* op = Yb + (size_t)grow * FOUT + cbase;
#pragma unroll
        for (int j = 0; j < 3; j++) op[j * 16] = f2bf(acc[i][j][r]);
      }
    }
  }
}

// ---------------- Clenshaw steps ----------------
// b_k = Y_k + 2*L*b_{k+1} - b_{k+2}   (all N x 288 bf16 panels; fp32 accumulate)
// XCD-partitioned jobs: each dispatch is exactly 8 jobs = (slot, feature-granule
// range); job = blockIdx.x & 7 so the HW round-robin workgroup->XCD mapping pins
// each job to one XCD. Per-XCD gather working set <= 2.88 MB (fits 4 MB L2) vs
// 5.76 MB/panel x nact slots before (L2 thrash -> HBM-bound random gathers).
// granule = 8 features = 16 B. In-place D==P is per-element (same thread).

struct Job {
  const unsigned short* H; // gather source b_{k+1}
  const unsigned short* Y; // additive Y_k
  const unsigned short* P; // b_{k+2} (may be null)
  unsigned short* D;       // dest b_k
  int goff, gcnt;          // granule offset / count within [0,36)
};
struct JobArgs { Job j[8]; };

__global__ __launch_bounds__(576) void cl_step_kernel(
    JobArgs a, const int* __restrict__ rowptr, const int* __restrict__ srcarr,
    const float* __restrict__ wn) {
  const int job = blockIdx.x & 7;
  const int nb = blockIdx.x >> 3;
  const Job J = a.j[job];
  const int g = J.gcnt;
  const int npb = 576 / g; // nodes per block
  const int t = threadIdx.x;
  if (t >= npb * g) return;
  const int node = nb * npb + t / g;
  if (node >= NN) return;
  const int off = (J.goff + t % g) * 8;
  const int rs = rowptr[node];
  const int re = rowptr[node + 1];
  const unsigned short* __restrict__ H = J.H;
  float acc[8];
#pragma unroll
  for (int q = 0; q < 8; q++) acc[q] = 0.f;
  for (int p = rs; p < re; ++p) {
    int r = srcarr[p];
    float w = wn[p];
    ushort8v h = *(const ushort8v*)(H + (size_t)r * FOUT + off);
#pragma unroll
    for (int q = 0; q < 8; q++) acc[q] += w * bf2f(h[q]);
  }
  size_t o = (size_t)node * FOUT + off;
  ushort8v y = *(const ushort8v*)(J.Y + o);
  ushort8v d;
  if (J.P) {
    ushort8v pp = *(const ushort8v*)(J.P + o);
#pragma unroll
    for (int q = 0; q < 8; q++) d[q] = f2bf(bf2f(y[q]) + 2.f * acc[q] - bf2f(pp[q]));
  } else {
#pragma unroll
    for (int q = 0; q < 8; q++) d[q] = f2bf(bf2f(y[q]) + 2.f * acc[q]);
  }
  *(ushort8v*)(J.D + o) = d;
}

// final: out[:, c*288 + f] = bias[f] + Y_0 + L*b_1 - b_2   (fp32 out)
struct FJob {
  const unsigned short* H; // b_1
  const unsigned short* Y; // Y_0
  const unsigned short* P; // b_2
  const float* B;          // bias
  int conv, goff, gcnt;
};
struct FJobArgs { FJob j[8]; };

__global__ __launch_bounds__(576) void cl_final_kernel(
    FJobArgs a, const int* __restrict__ rowptr, const int* __restrict__ srcarr,
    const float* __restrict__ wn, float* __restrict__ out) {
  const int job = blockIdx.x & 7;
  const int nb = blockIdx.x >> 3;
  const FJob J = a.j[job];
  const int g = J.gcnt;
  const int npb = 576 / g;
  const int t = threadIdx.x;
  if (t >= npb * g) return;
  const int node = nb * npb + t / g;
  if (node >= NN) return;
  const int off = (J.goff + t % g) * 8;
  const int rs = rowptr[node];
  const int re = rowptr[node + 1];
  const unsigned short* __restrict__ H = J.H;
  float acc[8];
#pragma unroll
  for (int q = 0; q < 8; q++) acc[q] = 0.f;
  for (int p = rs; p < re; ++p) {
    int r = srcarr[p];
    float w = wn[p];
    ushort8v h = *(const ushort8v*)(H + (size_t)r * FOUT + off);
#pragma unroll
    for (int q = 0; q < 8; q++) acc[q] += w * bf2f(h[q]);
  }
  size_t o = (size_t)node * FOUT + off;
  ushort8v y = *(const ushort8v*)(J.Y + o);
  ushort8v pp = *(const ushort8v*)(J.P + o);
  const float* bias = J.B + off;
  float r8[8];
#pragma unroll
  for (int q = 0; q < 8; q++)
    r8[q] = bias[q] + bf2f(y[q]) + acc[q] - bf2f(pp[q]);
  float* op = out + (size_t)node * FOUT_TOTAL + J.conv * FOUT + off;
  *(float4*)(op + 0) = make_float4(r8[0], r8[1], r8[2], r8[3]);
  *(float4*)(op + 4) = make_float4(r8[4], r8[5], r8[6], r8[7]);
}

// ---------------- launch ----------------

extern "C" void kernel_launch(void* const* d_in, const int* in_sizes, int n_in,
                              void* d_out, int out_size, void* d_ws, size_t ws_size,
                              hipStream_t stream) {
  const float* x = (const float*)d_in[0];
  const int* ei = (const int*)d_in[1];
  const float* W[4] = {(const float*)d_in[2], (const float*)d_in[4],
                       (const float*)d_in[6], (const float*)d_in[8]};
  const float* b[4] = {(const float*)d_in[3], (const float*)d_in[5],
                       (const float*)d_in[7], (const float*)d_in[9]};
  float* out = (float*)d_out;

  char* ws = (char*)d_ws;
  size_t off = 0;
  auto alloc = [&](size_t bytes) -> char* {
    char* p = ws + off;
    off += (bytes + 255) & ~(size_t)255;
    return p;
  };
  int* deg = (int*)alloc(NN * 4);
  int* indeg = (int*)alloc(NN * 4);
  int* rowptr = (int*)alloc((NN + 1) * 4);
  int* cursor = (int*)alloc(NN * 4);
  int* srcarr = (int*)alloc(NE * 4);
  float* wn = (float*)alloc(NE * 4);
  float* dinv = (float*)alloc(NN * 4);
  unsigned short* xb = (unsigned short*)alloc((size_t)NN * FIN * 2);       // bf16 x; reused as 4 spare panels
  unsigned short* Wt = (unsigned short*)alloc((size_t)NSLICE * WSL * 2);   // bf16 W^T
  unsigned short* Yall = (unsigned short*)alloc((size_t)NSLICE * NF * 2);  // bf16 Y panels

  hipMemsetAsync(deg, 0, NN * 4, stream);
  hipMemsetAsync(indeg, 0, NN * 4, stream);

  deg_kernel<<<(NE + 255) / 256, 256, 0, stream>>>(ei, deg, indeg);
  dinv_kernel<<<(NN + 255) / 256, 256, 0, stream>>>(deg, dinv);
  scan_kernel<<<1, 256, 0, stream>>>(indeg, rowptr, cursor);
  scatter_kernel<<<(NE + 255) / 256, 256, 0, stream>>>(ei, dinv, cursor, srcarr, wn);
  wtrans_kernel<<<(NSLICE * WSL + 255) / 256, 256, 0, stream>>>(W[0], W[1], W[2], W[3], Wt);
  xcast_kernel<<<(NN * FIN / 4 + 255) / 256, 256, 0, stream>>>(x, xb);

  // all 22 GEMMs in one dispatch; x = (slice,ntile) fastest for A-tile L2 reuse
  {
    dim3 grid(3 * NSLICE, (NN + 127) / 128);
    gemm_mfma_kernel<<<grid, 256, 0, stream>>>(xb, Wt, Yall);
  }

  // ---- Clenshaw schedule (host-side bookkeeping) ----
  const int nK[4] = {4, 5, 6, 7};
  const int st[4] = {0, 4, 9, 15};
  unsigned short* S[4]; // spare panels alias xb (xb no longer needed after GEMM)
  for (int c = 0; c < 4; c++) S[c] = xb + (size_t)c * NF;

  struct Slot {
    const unsigned short* H;
    const unsigned short* Y;
    const unsigned short* P;
    unsigned short* D;
  };
  Slot sched[5][4];
  int nact[5] = {0, 0, 0, 0, 0};
  struct FSlot {
    const unsigned short* H;
    const unsigned short* Y;
    const unsigned short* P;
    const float* B;
    int conv;
  };
  FSlot fs[4];

  for (int c = 3; c >= 0; c--) {
    int n = nK[c] - 1;        // Clenshaw degree (props per conv)
    int s0 = 6 - n;           // first global step for this conv
    unsigned short* Yn = Yall + (size_t)(st[c] + n) * NF; // holds b_n = Y_n initially
    unsigned short* A = S[c];
    for (int p = 1; p <= n; p++) {
      int s = s0 + p - 1;
      if (p < n) {
        unsigned short* H = (p & 1) ? Yn : A;
        unsigned short* D = (p & 1) ? A : Yn;
        int j = nact[s]++;
        sched[s][j].H = H;
        sched[s][j].Y = Yall + (size_t)(st[c] + n - p) * NF;
        sched[s][j].P = (p == 1) ? nullptr : D; // in-place over b_{k+2}
        sched[s][j].D = D;
      } else { // final at s == 5
        int j = 3 - c;
        fs[j].H = ((n - 1) & 1) ? A : Yn; // loc(b_1)
        fs[j].P = ((n - 2) & 1) ? A : Yn; // loc(b_2)
        fs[j].Y = Yall + (size_t)st[c] * NF;
        fs[j].B = b[c];
        fs[j].conv = c;
      }
    }
  }

  auto nb_for = [](int g) { int npb = 576 / g; return (NN + npb - 1) / npb; };

  for (int s = 0; s < 5; s++) {
    int n = nact[s];
    int slts[8], offs[8], cnts[8];
    if (n == 1) {
      const int cs[8] = {5, 5, 5, 5, 4, 4, 4, 4};
      int o = 0;
      for (int k = 0; k < 8; k++) { slts[k] = 0; offs[k] = o; cnts[k] = cs[k]; o += cs[k]; }
    } else if (n == 2) {
      for (int k = 0; k < 8; k++) { slts[k] = k >> 2; offs[k] = (k & 3) * 9; cnts[k] = 9; }
    } else if (n == 3) {
      int k = 0;
      for (int sl = 0; sl < 2; sl++)
        for (int i = 0; i < 3; i++) { slts[k] = sl; offs[k] = i * 12; cnts[k] = 12; k++; }
      for (int i = 0; i < 2; i++) { slts[k] = 2; offs[k] = i * 18; cnts[k] = 18; k++; }
    } else { // n == 4
      for (int k = 0; k < 8; k++) { slts[k] = k >> 1; offs[k] = (k & 1) * 18; cnts[k] = 18; }
    }
    JobArgs ja;
    int maxNB = 0;
    for (int k = 0; k < 8; k++) {
      const Slot& sl = sched[s][slts[k]];
      ja.j[k].H = sl.H; ja.j[k].Y = sl.Y; ja.j[k].P = sl.P; ja.j[k].D = sl.D;
      ja.j[k].goff = offs[k]; ja.j[k].gcnt = cnts[k];
      int nb = nb_for(cnts[k]);
      if (nb > maxNB) maxNB = nb;
    }
    cl_step_kernel<<<8 * maxNB, 576, 0, stream>>>(ja, rowptr, srcarr, wn);
  }

  {
    FJobArgs fja;
    for (int k = 0; k < 8; k++) {
      const FSlot& f = fs[k >> 1];
      fja.j[k].H = f.H; fja.j[k].Y = f.Y; fja.j[k].P = f.P; fja.j[k].B = f.B;
      fja.j[k].conv = f.conv;
      fja.j[k].goff = (k & 1) * 18; fja.j[k].gcnt = 18;
    }
    cl_final_kernel<<<8 * nb_for(18), 576, 0, stream>>>(fja, rowptr, srcarr, wn, out);
  }
}

// Round 3
// 728.321 us; speedup vs baseline: 1.0544x; 1.0522x over previous
//
#include <hip/hip_runtime.h>

#define NN 10000
#define NE 160000
#define FIN 1152
#define FOUT 288
#define FOUT_TOTAL 1152
#define NF (NN * FOUT)          /* 2,880,000 elems per N x 288 panel */
#define WSL (FIN * FOUT)        /* 331,776 elems per (conv,k) weight slice */
#define NSLICE 22

typedef __attribute__((ext_vector_type(8))) short short8;
typedef __attribute__((ext_vector_type(8))) unsigned short ushort8v;
typedef __attribute__((ext_vector_type(4))) float floatx4;

__device__ __forceinline__ unsigned short f2bf(float f) {
  unsigned int u = __float_as_uint(f);
  u += 0x7FFF + ((u >> 16) & 1); // round-to-nearest-even
  return (unsigned short)(u >> 16);
}
__device__ __forceinline__ float bf2f(unsigned short u) {
  return __uint_as_float(((unsigned int)u) << 16);
}

// async global->LDS, 16B per lane. LDS dest MUST be wave-uniform base + lane*16.
__device__ __forceinline__ void async_copy16(void* lds, const void* gmem) {
  __builtin_amdgcn_global_load_lds(
      (const __attribute__((address_space(1))) unsigned int*)gmem,
      (__attribute__((address_space(3))) unsigned int*)lds, 16, 0, 0);
}

// ---------------- degree / normalization ----------------

__global__ void deg_kernel(const int* __restrict__ ei, int* __restrict__ deg,
                           int* __restrict__ indeg) {
  int e = blockIdx.x * 256 + threadIdx.x;
  if (e < NE) {
    atomicAdd(&deg[ei[e]], 1);        // out-degree by source (row)
    atomicAdd(&indeg[ei[NE + e]], 1); // in-degree by target (col)
  }
}

__global__ void dinv_kernel(const int* __restrict__ deg, float* __restrict__ dinv) {
  int i = blockIdx.x * 256 + threadIdx.x;
  if (i < NN) {
    int d = deg[i];
    dinv[i] = d > 0 ? rsqrtf((float)d) : 0.0f;
  }
}

// single-block exclusive scan of indeg -> rowptr (and cursor copy)
__global__ void scan_kernel(const int* __restrict__ indeg, int* __restrict__ rowptr,
                            int* __restrict__ cursor) {
  __shared__ int s[256];
  __shared__ int carry_s;
  if (threadIdx.x == 0) carry_s = 0;
  __syncthreads();
  for (int base = 0; base < NN; base += 256) {
    int i = base + threadIdx.x;
    int v = (i < NN) ? indeg[i] : 0;
    s[threadIdx.x] = v;
    __syncthreads();
    for (int off = 1; off < 256; off <<= 1) {
      int t = (threadIdx.x >= off) ? s[threadIdx.x - off] : 0;
      __syncthreads();
      s[threadIdx.x] += t;
      __syncthreads();
    }
    int excl = s[threadIdx.x] - v + carry_s;
    if (i < NN) { rowptr[i] = excl; cursor[i] = excl; }
    __syncthreads();
    if (threadIdx.x == 0) carry_s += s[255];
    __syncthreads();
  }
  if (threadIdx.x == 0) rowptr[NN] = carry_s;
}

__global__ void scatter_kernel(const int* __restrict__ ei, const float* __restrict__ dinv,
                               int* __restrict__ cursor, int* __restrict__ srcarr,
                               float* __restrict__ wn) {
  int e = blockIdx.x * 256 + threadIdx.x;
  if (e < NE) {
    int r = ei[e], c = ei[NE + e];
    int pos = atomicAdd(&cursor[c], 1);
    srcarr[pos] = r;
    wn[pos] = -(dinv[r] * dinv[c]);
  }
}

// ---------------- weight transpose+cast: Wt[slice][o][f] bf16 ----------------
__global__ void wtrans_kernel(const float* __restrict__ W0, const float* __restrict__ W1,
                              const float* __restrict__ W2, const float* __restrict__ W3,
                              unsigned short* __restrict__ Wt) {
  int i = blockIdx.x * 256 + threadIdx.x;
  if (i >= NSLICE * WSL) return;
  int s = i / WSL;
  int rem = i - s * WSL;
  int o = rem / FIN;
  int f = rem - o * FIN;
  int c, k;
  if (s < 4)       { c = 0; k = s; }
  else if (s < 9)  { c = 1; k = s - 4; }
  else if (s < 15) { c = 2; k = s - 9; }
  else             { c = 3; k = s - 15; }
  const float* W = (c == 0) ? W0 : (c == 1) ? W1 : (c == 2) ? W2 : W3;
  Wt[i] = f2bf(W[(size_t)k * WSL + (size_t)f * FOUT + o]);
}

// ---------------- x -> bf16 cast ----------------
__global__ void xcast_kernel(const float* __restrict__ x, unsigned short* __restrict__ xb) {
  int i = blockIdx.x * 256 + threadIdx.x; // one float4 group per thread
  if (i < NN * FIN / 4) {
    float4 v = *(const float4*)(x + (size_t)i * 4);
    ushort4 r;
    r.x = f2bf(v.x); r.y = f2bf(v.y); r.z = f2bf(v.z); r.w = f2bf(v.w);
    *(ushort4*)(xb + (size_t)i * 4) = r;
  }
}

// ---------------- MFMA GEMM: Y[slice] = bf16( xb @ Wt[slice]^T ) ----------------
// Block tile 128x96, K=1152 (BK=64), 4 waves in 2x2, wave tile 64x48 = 4x3 mfma frags.
// Grid: x = (slice, ntile) [66], y = mtile [79].
// LDS XOR-swizzle (T2, rule 21): global_load_lds writes lane-linear, so the
// swizzle is applied to the GLOBAL source column (chunk ^= row&7) and the same
// XOR on the ds_read column. Verified R2: SQ_LDS_BANK_CONFLICT 6.3e7 -> 0,
// 235 -> 187.7 us.
__global__ __launch_bounds__(256) void gemm_mfma_kernel(
    const unsigned short* __restrict__ Xb, const unsigned short* __restrict__ Wt,
    unsigned short* __restrict__ Yall) {
  const int bx = blockIdx.x;
  const int slice = bx / 3;
  const int n0 = (bx - slice * 3) * 96;
  const int m0 = blockIdx.y * 128;

  __shared__ unsigned short As[128][64]; // [m][k] rows of 128 B (chunk-swizzled)
  __shared__ unsigned short Bs[96][64];  // [o][f] (chunk-swizzled)

  const int tid = threadIdx.x;
  const int lane = tid & 63;
  const int wave = tid >> 6;
  const int wx = wave & 1;        // n-dir
  const int wy = wave >> 1;       // m-dir
  const int lm = lane & 15;
  const int hi = lane >> 4;       // 16B chunk sub-index within 64B k-phase

  floatx4 acc[4][3];
#pragma unroll
  for (int i = 0; i < 4; i++)
#pragma unroll
    for (int j = 0; j < 3; j++) acc[i][j] = (floatx4){0.f, 0.f, 0.f, 0.f};

  const unsigned short* Wbase = Wt + (size_t)slice * WSL;

  for (int f0 = 0; f0 < FIN; f0 += 64) {
    __syncthreads(); // protect LDS from previous iteration's readers
    // stage A: 128 rows x 128 B, lane-linear LDS dest, swizzled global source
#pragma unroll
    for (int i = 0; i < 4; i++) {
      int idx = i * 256 + tid;
      int row = idx >> 3;
      int ck = idx & 7;
      int gr = m0 + row;
      gr = gr < NN ? gr : NN - 1; // clamp (masked at store)
      async_copy16((char*)&As[0][0] + idx * 16,
                   (const char*)Xb + ((size_t)gr * FIN + f0) * 2 + ((ck ^ (row & 7)) << 4));
    }
    // stage B: 96 rows x 128 B
#pragma unroll
    for (int i = 0; i < 3; i++) {
      int idx = i * 256 + tid;
      int row = idx >> 3;
      int ck = idx & 7;
      async_copy16((char*)&Bs[0][0] + idx * 16,
                   (const char*)Wbase + ((size_t)(n0 + row) * FIN + f0) * 2 + ((ck ^ (row & 7)) << 4));
    }
    __syncthreads();
#pragma unroll
    for (int s = 0; s < 2; s++) {
      short8 a[4], b[3];
#pragma unroll
      for (int i = 0; i < 4; i++) {
        int ar = wy * 64 + i * 16 + lm;
        a[i] = *(const short8*)((const char*)&As[ar][0] + (((s * 4 + hi) ^ (ar & 7)) << 4));
      }
#pragma unroll
      for (int j = 0; j < 3; j++) {
        int br = wx * 48 + j * 16 + lm;
        b[j] = *(const short8*)((const char*)&Bs[br][0] + (((s * 4 + hi) ^ (br & 7)) << 4));
      }
#pragma unroll
      for (int i = 0; i < 4; i++)
#pragma unroll
        for (int j = 0; j < 3; j++)
          acc[i][j] = __builtin_amdgcn_mfma_f32_16x16x32_bf16(a[i], b[j], acc[i][j], 0, 0, 0);
    }
  }
  // epilogue: C/D layout col=lane&15, row=(lane>>4)*4+reg -> bf16 Y panel
  unsigned short* Yb = Yall + (size_t)slice * NF;
  const int cbase = n0 + wx * 48 + lm;
  const int rbase = (lane >> 4) * 4;
#pragma unroll
  for (int i = 0; i < 4; i++) {
#pragma unroll
    for (int r = 0; r < 4; r++) {
      int grow = m0 + wy * 64 + i * 16 + rbase + r;
      if (grow < NN) {
        unsigned short* op = Yb + (size_t)grow * FOUT + cbase;
#pragma unroll
        for (int j = 0; j < 3; j++) op[j * 16] = f2bf(acc[i][j][r]);
      }
    }
  }
}

// ---------------- Clenshaw steps (slot-FUSED for memory-level parallelism) ----
// b_k = Y_k + 2*L*b_{k+1} - b_{k+2}   (all N x 288 bf16 panels; fp32 accumulate)
// R2 evidence: gathers are LATENCY-bound, not L2-capacity-bound (XCD pinning
// with L2-fit working sets bought 0). Fix: all nact slots of a step share the
// same edge list -> fuse into one kernel; each edge iteration issues NACT
// independent panel gathers (x U edge unroll) = up to 8 loads in flight, and
// srcarr/wn are loaded once instead of nact times. 18 latency-serial
// slot-instances collapse into 6 latency-parallel dispatches.
// Block: 576 threads = 16 nodes x 36 lanes, 16B (8 bf16) per lane.
// template<NACT> keeps all array indices compile-time (no scratch).

struct StepA {
  const unsigned short* H[4]; // gather source  b_{k+1}  (per slot)
  const unsigned short* Y[4]; // additive Y_k
  const unsigned short* P[4]; // b_{k+2} (may be null; wave-uniform branch)
  unsigned short* D[4];       // dest b_k
};

template <int NACT>
__global__ __launch_bounds__(576) void cl_step_fused(
    StepA a, const int* __restrict__ rowptr, const int* __restrict__ srcarr,
    const float* __restrict__ wn) {
  const int t = threadIdx.x;
  const int ln = t % 36;
  const int node = blockIdx.x * 16 + t / 36;
  if (node >= NN) return;
  const int off = ln * 8;
  const int rs = rowptr[node];
  const int re = rowptr[node + 1];
  float acc[NACT][8];
#pragma unroll
  for (int s = 0; s < NACT; s++)
#pragma unroll
    for (int q = 0; q < 8; q++) acc[s][q] = 0.f;

  constexpr int U = (NACT <= 2) ? 4 : 2; // edge unroll: keep ~8 loads in flight
  int p = rs;
  for (; p + U <= re; p += U) {
    int r[U];
    float w[U];
#pragma unroll
    for (int u = 0; u < U; u++) { r[u] = srcarr[p + u]; w[u] = wn[p + u]; }
    ushort8v h[U][NACT];
#pragma unroll
    for (int u = 0; u < U; u++)
#pragma unroll
      for (int s = 0; s < NACT; s++)
        h[u][s] = *(const ushort8v*)(a.H[s] + (size_t)r[u] * FOUT + off);
#pragma unroll
    for (int u = 0; u < U; u++)
#pragma unroll
      for (int s = 0; s < NACT; s++)
#pragma unroll
        for (int q = 0; q < 8; q++) acc[s][q] += w[u] * bf2f(h[u][s][q]);
  }
  for (; p < re; ++p) {
    int r = srcarr[p];
    float w = wn[p];
#pragma unroll
    for (int s = 0; s < NACT; s++) {
      ushort8v hh = *(const ushort8v*)(a.H[s] + (size_t)r * FOUT + off);
#pragma unroll
      for (int q = 0; q < 8; q++) acc[s][q] += w * bf2f(hh[q]);
    }
  }

  size_t o = (size_t)node * FOUT + off;
#pragma unroll
  for (int s = 0; s < NACT; s++) {
    ushort8v y = *(const ushort8v*)(a.Y[s] + o);
    ushort8v d;
    if (a.P[s]) {
      ushort8v pp = *(const ushort8v*)(a.P[s] + o);
#pragma unroll
      for (int q = 0; q < 8; q++) d[q] = f2bf(bf2f(y[q]) + 2.f * acc[s][q] - bf2f(pp[q]));
    } else {
#pragma unroll
      for (int q = 0; q < 8; q++) d[q] = f2bf(bf2f(y[q]) + 2.f * acc[s][q]);
    }
    *(ushort8v*)(a.D[s] + o) = d;
  }
}

// final: out[:, c*288 + f] = bias[f] + Y_0 + L*b_1 - b_2 (fp32 out), all 4 convs fused
struct FinalA {
  const unsigned short* H[4]; // b_1
  const unsigned short* Y[4]; // Y_0
  const unsigned short* P[4]; // b_2
  const float* B[4];          // bias
  int conv[4];
};

__global__ __launch_bounds__(576) void cl_final_fused(
    FinalA a, const int* __restrict__ rowptr, const int* __restrict__ srcarr,
    const float* __restrict__ wn, float* __restrict__ out) {
  const int t = threadIdx.x;
  const int ln = t % 36;
  const int node = blockIdx.x * 16 + t / 36;
  if (node >= NN) return;
  const int off = ln * 8;
  const int rs = rowptr[node];
  const int re = rowptr[node + 1];
  float acc[4][8];
#pragma unroll
  for (int s = 0; s < 4; s++)
#pragma unroll
    for (int q = 0; q < 8; q++) acc[s][q] = 0.f;

  constexpr int U = 2;
  int p = rs;
  for (; p + U <= re; p += U) {
    int r[U];
    float w[U];
#pragma unroll
    for (int u = 0; u < U; u++) { r[u] = srcarr[p + u]; w[u] = wn[p + u]; }
    ushort8v h[U][4];
#pragma unroll
    for (int u = 0; u < U; u++)
#pragma unroll
      for (int s = 0; s < 4; s++)
        h[u][s] = *(const ushort8v*)(a.H[s] + (size_t)r[u] * FOUT + off);
#pragma unroll
    for (int u = 0; u < U; u++)
#pragma unroll
      for (int s = 0; s < 4; s++)
#pragma unroll
        for (int q = 0; q < 8; q++) acc[s][q] += w[u] * bf2f(h[u][s][q]);
  }
  for (; p < re; ++p) {
    int r = srcarr[p];
    float w = wn[p];
#pragma unroll
    for (int s = 0; s < 4; s++) {
      ushort8v hh = *(const ushort8v*)(a.H[s] + (size_t)r * FOUT + off);
#pragma unroll
      for (int q = 0; q < 8; q++) acc[s][q] += w * bf2f(hh[q]);
    }
  }

  size_t o = (size_t)node * FOUT + off;
#pragma unroll
  for (int s = 0; s < 4; s++) {
    ushort8v y = *(const ushort8v*)(a.Y[s] + o);
    ushort8v pp = *(const ushort8v*)(a.P[s] + o);
    const float* bias = a.B[s] + off;
    float r8[8];
#pragma unroll
    for (int q = 0; q < 8; q++)
      r8[q] = bias[q] + bf2f(y[q]) + acc[s][q] - bf2f(pp[q]);
    float* op = out + (size_t)node * FOUT_TOTAL + a.conv[s] * FOUT + off;
    *(float4*)(op + 0) = make_float4(r8[0], r8[1], r8[2], r8[3]);
    *(float4*)(op + 4) = make_float4(r8[4], r8[5], r8[6], r8[7]);
  }
}

// ---------------- launch ----------------

extern "C" void kernel_launch(void* const* d_in, const int* in_sizes, int n_in,
                              void* d_out, int out_size, void* d_ws, size_t ws_size,
                              hipStream_t stream) {
  const float* x = (const float*)d_in[0];
  const int* ei = (const int*)d_in[1];
  const float* W[4] = {(const float*)d_in[2], (const float*)d_in[4],
                       (const float*)d_in[6], (const float*)d_in[8]};
  const float* b[4] = {(const float*)d_in[3], (const float*)d_in[5],
                       (const float*)d_in[7], (const float*)d_in[9]};
  float* out = (float*)d_out;

  char* ws = (char*)d_ws;
  size_t off = 0;
  auto alloc = [&](size_t bytes) -> char* {
    char* p = ws + off;
    off += (bytes + 255) & ~(size_t)255;
    return p;
  };
  int* deg = (int*)alloc(NN * 4);
  int* indeg = (int*)alloc(NN * 4);
  int* rowptr = (int*)alloc((NN + 1) * 4);
  int* cursor = (int*)alloc(NN * 4);
  int* srcarr = (int*)alloc(NE * 4);
  float* wn = (float*)alloc(NE * 4);
  float* dinv = (float*)alloc(NN * 4);
  unsigned short* xb = (unsigned short*)alloc((size_t)NN * FIN * 2);       // bf16 x; reused as 4 spare panels
  unsigned short* Wt = (unsigned short*)alloc((size_t)NSLICE * WSL * 2);   // bf16 W^T
  unsigned short* Yall = (unsigned short*)alloc((size_t)NSLICE * NF * 2);  // bf16 Y panels

  hipMemsetAsync(deg, 0, NN * 4, stream);
  hipMemsetAsync(indeg, 0, NN * 4, stream);

  deg_kernel<<<(NE + 255) / 256, 256, 0, stream>>>(ei, deg, indeg);
  dinv_kernel<<<(NN + 255) / 256, 256, 0, stream>>>(deg, dinv);
  scan_kernel<<<1, 256, 0, stream>>>(indeg, rowptr, cursor);
  scatter_kernel<<<(NE + 255) / 256, 256, 0, stream>>>(ei, dinv, cursor, srcarr, wn);
  wtrans_kernel<<<(NSLICE * WSL + 255) / 256, 256, 0, stream>>>(W[0], W[1], W[2], W[3], Wt);
  xcast_kernel<<<(NN * FIN / 4 + 255) / 256, 256, 0, stream>>>(x, xb);

  // all 22 GEMMs in one dispatch; x = (slice,ntile) fastest for A-tile L2 reuse
  {
    dim3 grid(3 * NSLICE, (NN + 127) / 128);
    gemm_mfma_kernel<<<grid, 256, 0, stream>>>(xb, Wt, Yall);
  }

  // ---- Clenshaw schedule (host-side bookkeeping) ----
  const int nK[4] = {4, 5, 6, 7};
  const int st[4] = {0, 4, 9, 15};
  unsigned short* S[4]; // spare panels alias xb (xb no longer needed after GEMM)
  for (int c = 0; c < 4; c++) S[c] = xb + (size_t)c * NF;

  StepA sched[5];
  int nact[5] = {0, 0, 0, 0, 0};
  FinalA fa;

  for (int c = 3; c >= 0; c--) {
    int n = nK[c] - 1;        // Clenshaw degree (props per conv)
    int s0 = 6 - n;           // first global step for this conv
    unsigned short* Yn = Yall + (size_t)(st[c] + n) * NF; // holds b_n = Y_n initially
    unsigned short* A = S[c];
    for (int p = 1; p <= n; p++) {
      int s = s0 + p - 1;
      if (p < n) {
        unsigned short* H = (p & 1) ? Yn : A;
        unsigned short* D = (p & 1) ? A : Yn;
        int j = nact[s]++;
        sched[s].H[j] = H;
        sched[s].Y[j] = Yall + (size_t)(st[c] + n - p) * NF;
        sched[s].P[j] = (p == 1) ? nullptr : D; // in-place over b_{k+2}
        sched[s].D[j] = D;
      } else { // final at s == 5
        int j = 3 - c;
        fa.H[j] = ((n - 1) & 1) ? A : Yn; // loc(b_1)
        fa.P[j] = ((n - 2) & 1) ? A : Yn; // loc(b_2)
        fa.Y[j] = Yall + (size_t)st[c] * NF;
        fa.B[j] = b[c];
        fa.conv[j] = c;
      }
    }
  }

  // pad unused slots with slot 0 (never dereferenced: template bound = nact)
  for (int s = 0; s < 5; s++)
    for (int j = nact[s]; j < 4; j++) {
      sched[s].H[j] = sched[s].H[0];
      sched[s].Y[j] = sched[s].Y[0];
      sched[s].P[j] = sched[s].P[0];
      sched[s].D[j] = sched[s].D[0];
    }

  const int grid_cl = NN / 16; // 625
  for (int s = 0; s < 5; s++) {
    switch (nact[s]) {
      case 1: cl_step_fused<1><<<grid_cl, 576, 0, stream>>>(sched[s], rowptr, srcarr, wn); break;
      case 2: cl_step_fused<2><<<grid_cl, 576, 0, stream>>>(sched[s], rowptr, srcarr, wn); break;
      case 3: cl_step_fused<3><<<grid_cl, 576, 0, stream>>>(sched[s], rowptr, srcarr, wn); break;
      default: cl_step_fused<4><<<grid_cl, 576, 0, stream>>>(sched[s], rowptr, srcarr, wn); break;
    }
  }
  cl_final_fused<<<grid_cl, 576, 0, stream>>>(fa, rowptr, srcarr, wn, out);
}